// Round 1
// baseline (3400.628 us; speedup 1.0000x reference)
//
#include <hip/hip_runtime.h>

#define NA 100000
#define NB 800000
#define DEG 32
#define FDIM 64
// HID = 128

typedef __bf16 bf16x8 __attribute__((ext_vector_type(8)));
typedef float f32x4 __attribute__((ext_vector_type(4)));

#define MFMA(a, b, c) __builtin_amdgcn_mfma_f32_16x16x32_bf16(a, b, c, 0, 0, 0)

__device__ __forceinline__ float softplus_f(float x) {
  float ax = __builtin_fabsf(x);
  return fmaxf(x, 0.0f) + __logf(1.0f + __expf(-ax));
}

__device__ __forceinline__ bf16x8 pack8(const float* t) {
  bf16x8 r;
#pragma unroll
  for (int j = 0; j < 8; ++j) r[j] = (__bf16)t[j];
  return r;
}

// ---------------------------------------------------------------------------
// Pack weights (K x N fp32 row-major) into MFMA B-fragment order, bf16.
// Fragment (kstep, nt): lane holds B[k = kstep*32 + (lane>>4)*8 + j][n = nt*16 + (lane&15)]
// Packed: frag_index = kstep*NT + nt; 64 lanes * 16B contiguous per frag.
// ws frag offsets (in bf16x8 units): Wb1:0  Wb2:4096  Wa1:5120  Wa2:9216  (end 10240)
// ---------------------------------------------------------------------------
__global__ void pack_kernel(const float* __restrict__ Wb1, const float* __restrict__ Wb2,
                            const float* __restrict__ Wa1, const float* __restrict__ Wa2,
                            bf16x8* __restrict__ dst) {
  int tid = blockIdx.x * 256 + threadIdx.x;
  const float* W;
  int NT, s;
  bf16x8* out;
  if (tid < 4096)       { W = Wb1; NT = 8; out = dst;        s = tid; }
  else if (tid < 5120)  { W = Wb2; NT = 4; out = dst + 4096; s = tid - 4096; }
  else if (tid < 9216)  { W = Wa1; NT = 8; out = dst + 5120; s = tid - 5120; }
  else if (tid < 10240) { W = Wa2; NT = 4; out = dst + 9216; s = tid - 9216; }
  else return;
  int N = NT * 16;
  int lane = s & 63, fi = s >> 6;
  int nt = fi % NT, kstep = fi / NT;
  int n = nt * 16 + (lane & 15);
  int k0 = kstep * 32 + (lane >> 4) * 8;
  bf16x8 v;
#pragma unroll
  for (int j = 0; j < 8; ++j) v[j] = (__bf16)W[(size_t)(k0 + j) * N + n];
  out[s] = v;
}

// ---------------------------------------------------------------------------
// Bond update: per wave 32 bonds.  comb = [atom_i | atom_j | bond | g] (256)
// layer1 -> softplus -> LDS (D-layout -> A-layout) -> layer2 -> +bias +resid
// ---------------------------------------------------------------------------
__global__ __launch_bounds__(512, 2) void bond_kernel(
    const float* __restrict__ atom_f, const float* __restrict__ bond_f,
    const float* __restrict__ g, const float* __restrict__ bb1,
    const float* __restrict__ bb2, const int* __restrict__ ab_idx,
    const bf16x8* __restrict__ w1p, const bf16x8* __restrict__ w2p,
    float* __restrict__ out_bonds, float* __restrict__ psums) {
  __shared__ bf16x8 lW1[4096];        // 64 KB
  __shared__ bf16x8 lW2[1024];        // 16 KB
  __shared__ __bf16 hbuf[8][32 * 132];  // 8448 B per wave

  const int t = threadIdx.x;
  for (int i = t; i < 4096; i += 512) lW1[i] = w1p[i];
  for (int i = t; i < 1024; i += 512) lW2[i] = w2p[i];
  __syncthreads();

  const int w = t >> 6;
  const int l = t & 63;
  const int q = l >> 4;
  const int c = l & 15;
  const int base = blockIdx.x * 256 + w * 32;

  // ---- gather A fragments straight into registers ----
  bf16x8 afrag[2][8];
#pragma unroll
  for (int mt = 0; mt < 2; ++mt) {
    const int b = base + mt * 16 + c;
    const int ai = ab_idx[2 * b];
    const int aj = ab_idx[2 * b + 1];
    const float* s0 = atom_f + (size_t)ai * FDIM;
    const float* s1 = atom_f + (size_t)aj * FDIM;
    const float* s2 = bond_f + (size_t)b * FDIM;
#pragma unroll
    for (int ks = 0; ks < 8; ++ks) {
      const float* src = (ks < 2 ? s0 : ks < 4 ? s1 : ks < 6 ? s2 : g) +
                         (ks & 1) * 32 + q * 8;
      float tmp[8];
      *(f32x4*)(tmp) = *(const f32x4*)(src);
      *(f32x4*)(tmp + 4) = *(const f32x4*)(src + 4);
      afrag[mt][ks] = pack8(tmp);
    }
  }

  // ---- layer 1: X(32x256) @ W1(256x128) ----
  f32x4 acc1[2][8] = {};
#pragma unroll
  for (int ks = 0; ks < 8; ++ks) {
#pragma unroll
    for (int nt = 0; nt < 8; ++nt) {
      bf16x8 bf = lW1[(ks * 8 + nt) * 64 + l];
      acc1[0][nt] = MFMA(afrag[0][ks], bf, acc1[0][nt]);
      acc1[1][nt] = MFMA(afrag[1][ks], bf, acc1[1][nt]);
    }
  }

  // ---- bias + softplus, write hidden to LDS row-major (stride 132 bf16) ----
  __bf16* hb = hbuf[w];
#pragma unroll
  for (int nt = 0; nt < 8; ++nt) {
    const int h = nt * 16 + c;
    const float b1 = bb1[h];
#pragma unroll
    for (int mt = 0; mt < 2; ++mt)
#pragma unroll
      for (int r = 0; r < 4; ++r)
        hb[(mt * 16 + q * 4 + r) * 132 + h] =
            (__bf16)softplus_f(acc1[mt][nt][r] + b1);
  }
  __syncthreads();

  // ---- layer 2: H(32x128) @ W2(128x64) ----
  bf16x8 a2[2][4];
#pragma unroll
  for (int mt = 0; mt < 2; ++mt)
#pragma unroll
    for (int k2 = 0; k2 < 4; ++k2) {
      const __bf16* p = hb + (mt * 16 + c) * 132 + k2 * 32 + q * 8;
      union { unsigned long long u[2]; bf16x8 v; } tmp;
      tmp.u[0] = *(const unsigned long long*)(p);
      tmp.u[1] = *(const unsigned long long*)(p + 4);
      a2[mt][k2] = tmp.v;
    }
  f32x4 acc2[2][4] = {};
#pragma unroll
  for (int k2 = 0; k2 < 4; ++k2)
#pragma unroll
    for (int nt2 = 0; nt2 < 4; ++nt2) {
      bf16x8 bf = lW2[(k2 * 4 + nt2) * 64 + l];
      acc2[0][nt2] = MFMA(a2[0][k2], bf, acc2[0][nt2]);
      acc2[1][nt2] = MFMA(a2[1][k2], bf, acc2[1][nt2]);
    }

  // ---- epilogue: + bb2 + residual, store, column partial sums ----
  float colpart[4] = {0.f, 0.f, 0.f, 0.f};
#pragma unroll
  for (int nt2 = 0; nt2 < 4; ++nt2) {
    const int col = nt2 * 16 + c;
    const float b2 = bb2[col];
#pragma unroll
    for (int mt = 0; mt < 2; ++mt)
#pragma unroll
      for (int r = 0; r < 4; ++r) {
        const int b = base + mt * 16 + q * 4 + r;
        float v = acc2[mt][nt2][r] + b2 + bond_f[(size_t)b * FDIM + col];
        out_bonds[(size_t)b * FDIM + col] = v;
        colpart[nt2] += v;
      }
  }
#pragma unroll
  for (int nt2 = 0; nt2 < 4; ++nt2) {
    colpart[nt2] += __shfl_xor(colpart[nt2], 16, 64);
    colpart[nt2] += __shfl_xor(colpart[nt2], 32, 64);
  }
  if (l < 16) {
    float* slot = psums + ((size_t)blockIdx.x * 8 + w) * 64;
#pragma unroll
    for (int nt2 = 0; nt2 < 4; ++nt2) slot[nt2 * 16 + l] = colpart[nt2];
  }
}

// ---------------------------------------------------------------------------
// Atom update: comb = [atom | agg | atom | g]; agg = masked mean of updated bonds
// ---------------------------------------------------------------------------
__global__ __launch_bounds__(512, 2) void atom_kernel(
    const float* __restrict__ atom_f, const float* __restrict__ g,
    const float* __restrict__ ba1, const float* __restrict__ ba2,
    const int* __restrict__ ba_idx, const float* __restrict__ ub,
    const bf16x8* __restrict__ w1p, const bf16x8* __restrict__ w2p,
    float* __restrict__ out_atoms, float* __restrict__ psums) {
  __shared__ bf16x8 lW1[4096];
  __shared__ bf16x8 lW2[1024];
  __shared__ __bf16 hbuf[8][32 * 132];

  const int t = threadIdx.x;
  for (int i = t; i < 4096; i += 512) lW1[i] = w1p[i];
  for (int i = t; i < 1024; i += 512) lW2[i] = w2p[i];
  __syncthreads();

  const int w = t >> 6;
  const int l = t & 63;
  const int q = l >> 4;
  const int c = l & 15;
  const int base = blockIdx.x * 256 + w * 32;
  const bool active = base < NA;  // 100000 = 390*256 + 5*32: waves fully in/out

  bf16x8 afrag[2][8];
  f32x4 acc1[2][8] = {};
  __bf16* hb = hbuf[w];

  if (active) {
#pragma unroll
    for (int mt = 0; mt < 2; ++mt) {
      const int a = base + mt * 16 + c;
      const float* sa = atom_f + (size_t)a * FDIM;
      // atom chunks (positions 0 and 2 of concat)
#pragma unroll
      for (int ks = 0; ks < 2; ++ks) {
        const float* src = sa + ks * 32 + q * 8;
        float tmp[8];
        *(f32x4*)(tmp) = *(const f32x4*)(src);
        *(f32x4*)(tmp + 4) = *(const f32x4*)(src + 4);
        afrag[mt][ks] = pack8(tmp);
        afrag[mt][ks + 4] = afrag[mt][ks];
      }
      // aggregation of updated bonds (masked mean)
      f32x4 sA0 = {0,0,0,0}, sA1 = {0,0,0,0}, sB0 = {0,0,0,0}, sB1 = {0,0,0,0};
      int cnt = 0;
      const int* ip = ba_idx + (size_t)a * DEG;
#pragma unroll 4
      for (int d = 0; d < DEG; ++d) {
        int bi = ip[d];
        if (bi >= 0) {
          ++cnt;
          const float* br = ub + (size_t)bi * FDIM + q * 8;
          sA0 += *(const f32x4*)(br);
          sA1 += *(const f32x4*)(br + 4);
          sB0 += *(const f32x4*)(br + 32);
          sB1 += *(const f32x4*)(br + 36);
        }
      }
      const float inv = 1.0f / (float)(cnt < 1 ? 1 : cnt);
      float tA[8], tB[8];
      *(f32x4*)(tA) = sA0 * inv; *(f32x4*)(tA + 4) = sA1 * inv;
      *(f32x4*)(tB) = sB0 * inv; *(f32x4*)(tB + 4) = sB1 * inv;
      afrag[mt][2] = pack8(tA);
      afrag[mt][3] = pack8(tB);
      // global chunk
#pragma unroll
      for (int ks = 6; ks < 8; ++ks) {
        const float* src = g + (ks & 1) * 32 + q * 8;
        float tmp[8];
        *(f32x4*)(tmp) = *(const f32x4*)(src);
        *(f32x4*)(tmp + 4) = *(const f32x4*)(src + 4);
        afrag[mt][ks] = pack8(tmp);
      }
    }
#pragma unroll
    for (int ks = 0; ks < 8; ++ks) {
#pragma unroll
      for (int nt = 0; nt < 8; ++nt) {
        bf16x8 bf = lW1[(ks * 8 + nt) * 64 + l];
        acc1[0][nt] = MFMA(afrag[0][ks], bf, acc1[0][nt]);
        acc1[1][nt] = MFMA(afrag[1][ks], bf, acc1[1][nt]);
      }
    }
#pragma unroll
    for (int nt = 0; nt < 8; ++nt) {
      const int h = nt * 16 + c;
      const float b1 = ba1[h];
#pragma unroll
      for (int mt = 0; mt < 2; ++mt)
#pragma unroll
        for (int r = 0; r < 4; ++r)
          hb[(mt * 16 + q * 4 + r) * 132 + h] =
              (__bf16)softplus_f(acc1[mt][nt][r] + b1);
    }
  }
  __syncthreads();

  float colpart[4] = {0.f, 0.f, 0.f, 0.f};
  if (active) {
    bf16x8 a2[2][4];
#pragma unroll
    for (int mt = 0; mt < 2; ++mt)
#pragma unroll
      for (int k2 = 0; k2 < 4; ++k2) {
        const __bf16* p = hb + (mt * 16 + c) * 132 + k2 * 32 + q * 8;
        union { unsigned long long u[2]; bf16x8 v; } tmp;
        tmp.u[0] = *(const unsigned long long*)(p);
        tmp.u[1] = *(const unsigned long long*)(p + 4);
        a2[mt][k2] = tmp.v;
      }
    f32x4 acc2[2][4] = {};
#pragma unroll
    for (int k2 = 0; k2 < 4; ++k2)
#pragma unroll
      for (int nt2 = 0; nt2 < 4; ++nt2) {
        bf16x8 bf = lW2[(k2 * 4 + nt2) * 64 + l];
        acc2[0][nt2] = MFMA(a2[0][k2], bf, acc2[0][nt2]);
        acc2[1][nt2] = MFMA(a2[1][k2], bf, acc2[1][nt2]);
      }
#pragma unroll
    for (int nt2 = 0; nt2 < 4; ++nt2) {
      const int col = nt2 * 16 + c;
      const float b2 = ba2[col];
#pragma unroll
      for (int mt = 0; mt < 2; ++mt)
#pragma unroll
        for (int r = 0; r < 4; ++r) {
          const int a = base + mt * 16 + q * 4 + r;
          float v = acc2[mt][nt2][r] + b2 + atom_f[(size_t)a * FDIM + col];
          out_atoms[(size_t)a * FDIM + col] = v;
          colpart[nt2] += v;
        }
    }
  }
#pragma unroll
  for (int nt2 = 0; nt2 < 4; ++nt2) {
    colpart[nt2] += __shfl_xor(colpart[nt2], 16, 64);
    colpart[nt2] += __shfl_xor(colpart[nt2], 32, 64);
  }
  if (l < 16) {
    float* slot = psums + ((size_t)blockIdx.x * 8 + w) * 64;
#pragma unroll
    for (int nt2 = 0; nt2 < 4; ++nt2) slot[nt2 * 16 + l] = colpart[nt2];
  }
}

// ---------------------------------------------------------------------------
// Global update: reduce per-wave partials -> pooled means -> tiny fp32 MLP
// ---------------------------------------------------------------------------
__global__ void global_kernel(const float* __restrict__ g,
                              const float* __restrict__ Wg1,
                              const float* __restrict__ bg1,
                              const float* __restrict__ Wg2,
                              const float* __restrict__ bg2,
                              const float* __restrict__ bond_ps, int nb_slots,
                              const float* __restrict__ atom_ps, int na_slots,
                              float* __restrict__ out_global) {
  __shared__ float red[256];
  __shared__ float combg[192];
  __shared__ float hid[128];
  const int t = threadIdx.x;

  float acc = 0.f;
  for (size_t i = t; i < (size_t)nb_slots * 64; i += 256) acc += bond_ps[i];
  red[t] = acc;
  __syncthreads();
  if (t < 64)
    combg[64 + t] = (red[t] + red[t + 64] + red[t + 128] + red[t + 192]) / (float)NB;
  __syncthreads();

  acc = 0.f;
  for (size_t i = t; i < (size_t)na_slots * 64; i += 256) acc += atom_ps[i];
  red[t] = acc;
  __syncthreads();
  if (t < 64)
    combg[t] = (red[t] + red[t + 64] + red[t + 128] + red[t + 192]) / (float)NA;
  if (t >= 64 && t < 128) combg[128 + (t - 64)] = g[t - 64];
  __syncthreads();

  if (t < 128) {
    float s = bg1[t];
    for (int k = 0; k < 192; ++k) s += combg[k] * Wg1[k * 128 + t];
    hid[t] = softplus_f(s);
  }
  __syncthreads();
  if (t < 64) {
    float s = bg2[t];
    for (int h = 0; h < 128; ++h) s += hid[h] * Wg2[h * 64 + t];
    out_global[t] = s + g[t];
  }
}

// ---------------------------------------------------------------------------
extern "C" void kernel_launch(void* const* d_in, const int* in_sizes, int n_in,
                              void* d_out, int out_size, void* d_ws, size_t ws_size,
                              hipStream_t stream) {
  (void)in_sizes; (void)n_in; (void)out_size; (void)ws_size;
  const float* atom_f = (const float*)d_in[0];
  const float* bond_f = (const float*)d_in[1];
  const float* g      = (const float*)d_in[2];
  const float* Wb1 = (const float*)d_in[3];
  const float* bb1 = (const float*)d_in[4];
  const float* Wb2 = (const float*)d_in[5];
  const float* bb2 = (const float*)d_in[6];
  const float* Wa1 = (const float*)d_in[7];
  const float* ba1 = (const float*)d_in[8];
  const float* Wa2 = (const float*)d_in[9];
  const float* ba2 = (const float*)d_in[10];
  const float* Wg1 = (const float*)d_in[11];
  const float* bg1 = (const float*)d_in[12];
  const float* Wg2 = (const float*)d_in[13];
  const float* bg2 = (const float*)d_in[14];
  const int* ab_idx = (const int*)d_in[15];
  const int* ba_idx = (const int*)d_in[16];

  float* out        = (float*)d_out;
  float* out_atoms  = out;
  float* out_bonds  = out + (size_t)NA * FDIM;
  float* out_global = out + (size_t)NA * FDIM + (size_t)NB * FDIM;

  bf16x8* wp   = (bf16x8*)d_ws;
  float* ws_f  = (float*)d_ws;
  float* bond_ps = ws_f + 40960;                 // after 10240 frags * 16B
  float* atom_ps = bond_ps + (size_t)25000 * 64; // 3125 blocks * 8 waves
  const int na_blocks = (NA + 255) / 256;        // 391
  const int na_slots  = na_blocks * 8;           // 3128

  pack_kernel<<<40, 256, 0, stream>>>(Wb1, Wb2, Wa1, Wa2, wp);
  bond_kernel<<<NB / 256, 512, 0, stream>>>(atom_f, bond_f, g, bb1, bb2, ab_idx,
                                            wp, wp + 4096, out_bonds, bond_ps);
  atom_kernel<<<na_blocks, 512, 0, stream>>>(atom_f, g, ba1, ba2, ba_idx,
                                             out_bonds, wp + 5120, wp + 9216,
                                             out_atoms, atom_ps);
  global_kernel<<<1, 256, 0, stream>>>(g, Wg1, bg1, Wg2, bg2, bond_ps, 25000,
                                       atom_ps, na_slots, out_global);
}

// Round 2
// 783.257 us; speedup vs baseline: 4.3417x; 4.3417x over previous
//
#include <hip/hip_runtime.h>

#define NA 100000
#define NB 800000
#define DEG 32
#define FDIM 64
// HID = 128

typedef __bf16 bf16x8 __attribute__((ext_vector_type(8)));
typedef float f32x4 __attribute__((ext_vector_type(4)));

#define MFMA(a, b, c) __builtin_amdgcn_mfma_f32_16x16x32_bf16(a, b, c, 0, 0, 0)

__device__ __forceinline__ float softplus_f(float x) {
  float ax = __builtin_fabsf(x);
  return fmaxf(x, 0.0f) + __logf(1.0f + __expf(-ax));
}

__device__ __forceinline__ bf16x8 pack8(const float* t) {
  bf16x8 r;
#pragma unroll
  for (int j = 0; j < 8; ++j) r[j] = (__bf16)t[j];
  return r;
}

// ---------------------------------------------------------------------------
// Pack weights (K x N fp32 row-major) into MFMA B-fragment order, bf16.
// Fragment (kstep, nt): lane holds B[k = kstep*32 + (lane>>4)*8 + j][n = nt*16 + (lane&15)]
// ws frag offsets (bf16x8 units): Wb1:0  Wb2:4096  Wa1:5120  Wa2:9216  (end 10240)
// ---------------------------------------------------------------------------
__global__ void pack_kernel(const float* __restrict__ Wb1, const float* __restrict__ Wb2,
                            const float* __restrict__ Wa1, const float* __restrict__ Wa2,
                            bf16x8* __restrict__ dst) {
  int tid = blockIdx.x * 256 + threadIdx.x;
  const float* W;
  int NT, s;
  bf16x8* out;
  if (tid < 4096)       { W = Wb1; NT = 8; out = dst;        s = tid; }
  else if (tid < 5120)  { W = Wb2; NT = 4; out = dst + 4096; s = tid - 4096; }
  else if (tid < 9216)  { W = Wa1; NT = 8; out = dst + 5120; s = tid - 5120; }
  else if (tid < 10240) { W = Wa2; NT = 4; out = dst + 9216; s = tid - 9216; }
  else return;
  int N = NT * 16;
  int lane = s & 63, fi = s >> 6;
  int nt = fi % NT, kstep = fi / NT;
  int n = nt * 16 + (lane & 15);
  int k0 = kstep * 32 + (lane >> 4) * 8;
  bf16x8 v;
#pragma unroll
  for (int j = 0; j < 8; ++j) v[j] = (__bf16)W[(size_t)(k0 + j) * N + n];
  out[s] = v;
}

// ---------------------------------------------------------------------------
// Bond update: per wave 32 bonds.  comb = [atom_i | atom_j | bond | g] (256)
// layer1 -> softplus -> LDS (D-layout -> A-layout) -> layer2 -> +bias +resid
// Writes ONE 64-float column-sum row per block.
// ---------------------------------------------------------------------------
__global__ __launch_bounds__(512, 2) void bond_kernel(
    const float* __restrict__ atom_f, const float* __restrict__ bond_f,
    const float* __restrict__ g, const float* __restrict__ bb1,
    const float* __restrict__ bb2, const int* __restrict__ ab_idx,
    const bf16x8* __restrict__ w1p, const bf16x8* __restrict__ w2p,
    float* __restrict__ out_bonds, float* __restrict__ psums) {
  __shared__ bf16x8 lW1[4096];          // 64 KB
  __shared__ bf16x8 lW2[1024];          // 16 KB
  __shared__ __bf16 hbuf[8][32 * 132];  // 67.6 KB
  __shared__ float csum[8][64];         // 2 KB

  const int t = threadIdx.x;
  for (int i = t; i < 4096; i += 512) lW1[i] = w1p[i];
  for (int i = t; i < 1024; i += 512) lW2[i] = w2p[i];
  __syncthreads();

  const int w = t >> 6;
  const int l = t & 63;
  const int q = l >> 4;
  const int c = l & 15;
  const int base = blockIdx.x * 256 + w * 32;

  // ---- gather A fragments straight into registers ----
  bf16x8 afrag[2][8];
#pragma unroll
  for (int mt = 0; mt < 2; ++mt) {
    const int b = base + mt * 16 + c;
    const int ai = ab_idx[2 * b];
    const int aj = ab_idx[2 * b + 1];
    const float* s0 = atom_f + (size_t)ai * FDIM;
    const float* s1 = atom_f + (size_t)aj * FDIM;
    const float* s2 = bond_f + (size_t)b * FDIM;
#pragma unroll
    for (int ks = 0; ks < 8; ++ks) {
      const float* src = (ks < 2 ? s0 : ks < 4 ? s1 : ks < 6 ? s2 : g) +
                         (ks & 1) * 32 + q * 8;
      float tmp[8];
      *(f32x4*)(tmp) = *(const f32x4*)(src);
      *(f32x4*)(tmp + 4) = *(const f32x4*)(src + 4);
      afrag[mt][ks] = pack8(tmp);
    }
  }

  // ---- layer 1: X(32x256) @ W1(256x128) ----
  f32x4 acc1[2][8] = {};
#pragma unroll
  for (int ks = 0; ks < 8; ++ks) {
#pragma unroll
    for (int nt = 0; nt < 8; ++nt) {
      bf16x8 bf = lW1[(ks * 8 + nt) * 64 + l];
      acc1[0][nt] = MFMA(afrag[0][ks], bf, acc1[0][nt]);
      acc1[1][nt] = MFMA(afrag[1][ks], bf, acc1[1][nt]);
    }
  }

  // ---- bias + softplus, hidden to LDS row-major (stride 132 bf16) ----
  __bf16* hb = hbuf[w];
#pragma unroll
  for (int nt = 0; nt < 8; ++nt) {
    const int h = nt * 16 + c;
    const float b1 = bb1[h];
#pragma unroll
    for (int mt = 0; mt < 2; ++mt)
#pragma unroll
      for (int r = 0; r < 4; ++r)
        hb[(mt * 16 + q * 4 + r) * 132 + h] =
            (__bf16)softplus_f(acc1[mt][nt][r] + b1);
  }
  __syncthreads();

  // ---- layer 2: H(32x128) @ W2(128x64) ----
  bf16x8 a2[2][4];
#pragma unroll
  for (int mt = 0; mt < 2; ++mt)
#pragma unroll
    for (int k2 = 0; k2 < 4; ++k2) {
      const __bf16* p = hb + (mt * 16 + c) * 132 + k2 * 32 + q * 8;
      union { unsigned long long u[2]; bf16x8 v; } tmp;
      tmp.u[0] = *(const unsigned long long*)(p);
      tmp.u[1] = *(const unsigned long long*)(p + 4);
      a2[mt][k2] = tmp.v;
    }
  f32x4 acc2[2][4] = {};
#pragma unroll
  for (int k2 = 0; k2 < 4; ++k2)
#pragma unroll
    for (int nt2 = 0; nt2 < 4; ++nt2) {
      bf16x8 bf = lW2[(k2 * 4 + nt2) * 64 + l];
      acc2[0][nt2] = MFMA(a2[0][k2], bf, acc2[0][nt2]);
      acc2[1][nt2] = MFMA(a2[1][k2], bf, acc2[1][nt2]);
    }

  // ---- epilogue: + bb2 + residual, store, column partial sums ----
  float colpart[4] = {0.f, 0.f, 0.f, 0.f};
#pragma unroll
  for (int nt2 = 0; nt2 < 4; ++nt2) {
    const int col = nt2 * 16 + c;
    const float b2 = bb2[col];
#pragma unroll
    for (int mt = 0; mt < 2; ++mt)
#pragma unroll
      for (int r = 0; r < 4; ++r) {
        const int b = base + mt * 16 + q * 4 + r;
        float v = acc2[mt][nt2][r] + b2 + bond_f[(size_t)b * FDIM + col];
        out_bonds[(size_t)b * FDIM + col] = v;
        colpart[nt2] += v;
      }
  }
#pragma unroll
  for (int nt2 = 0; nt2 < 4; ++nt2) {
    colpart[nt2] += __shfl_xor(colpart[nt2], 16, 64);
    colpart[nt2] += __shfl_xor(colpart[nt2], 32, 64);
  }
  if (l < 16)
#pragma unroll
    for (int nt2 = 0; nt2 < 4; ++nt2) csum[w][nt2 * 16 + l] = colpart[nt2];
  __syncthreads();
  if (t < 64) {
    float s = 0.f;
#pragma unroll
    for (int wv = 0; wv < 8; ++wv) s += csum[wv][t];
    psums[(size_t)blockIdx.x * 64 + t] = s;
  }
}

// ---------------------------------------------------------------------------
// Atom update: comb = [atom | agg | atom | g]; agg = masked mean of updated bonds
// ---------------------------------------------------------------------------
__global__ __launch_bounds__(512, 2) void atom_kernel(
    const float* __restrict__ atom_f, const float* __restrict__ g,
    const float* __restrict__ ba1, const float* __restrict__ ba2,
    const int* __restrict__ ba_idx, const float* __restrict__ ub,
    const bf16x8* __restrict__ w1p, const bf16x8* __restrict__ w2p,
    float* __restrict__ out_atoms, float* __restrict__ psums) {
  __shared__ bf16x8 lW1[4096];
  __shared__ bf16x8 lW2[1024];
  __shared__ __bf16 hbuf[8][32 * 132];
  __shared__ float csum[8][64];

  const int t = threadIdx.x;
  for (int i = t; i < 4096; i += 512) lW1[i] = w1p[i];
  for (int i = t; i < 1024; i += 512) lW2[i] = w2p[i];
  __syncthreads();

  const int w = t >> 6;
  const int l = t & 63;
  const int q = l >> 4;
  const int c = l & 15;
  const int base = blockIdx.x * 256 + w * 32;
  const bool active = base < NA;  // 100000 = 390*256 + 5*32: waves fully in/out

  bf16x8 afrag[2][8];
  f32x4 acc1[2][8] = {};
  __bf16* hb = hbuf[w];

  if (active) {
#pragma unroll
    for (int mt = 0; mt < 2; ++mt) {
      const int a = base + mt * 16 + c;
      const float* sa = atom_f + (size_t)a * FDIM;
#pragma unroll
      for (int ks = 0; ks < 2; ++ks) {
        const float* src = sa + ks * 32 + q * 8;
        float tmp[8];
        *(f32x4*)(tmp) = *(const f32x4*)(src);
        *(f32x4*)(tmp + 4) = *(const f32x4*)(src + 4);
        afrag[mt][ks] = pack8(tmp);
        afrag[mt][ks + 4] = afrag[mt][ks];
      }
      // aggregation of updated bonds (masked mean)
      f32x4 sA0 = {0,0,0,0}, sA1 = {0,0,0,0}, sB0 = {0,0,0,0}, sB1 = {0,0,0,0};
      int cnt = 0;
      const int* ip = ba_idx + (size_t)a * DEG;
#pragma unroll 4
      for (int d = 0; d < DEG; ++d) {
        int bi = ip[d];
        if (bi >= 0) {
          ++cnt;
          const float* br = ub + (size_t)bi * FDIM + q * 8;
          sA0 += *(const f32x4*)(br);
          sA1 += *(const f32x4*)(br + 4);
          sB0 += *(const f32x4*)(br + 32);
          sB1 += *(const f32x4*)(br + 36);
        }
      }
      const float inv = 1.0f / (float)(cnt < 1 ? 1 : cnt);
      float tA[8], tB[8];
      *(f32x4*)(tA) = sA0 * inv; *(f32x4*)(tA + 4) = sA1 * inv;
      *(f32x4*)(tB) = sB0 * inv; *(f32x4*)(tB + 4) = sB1 * inv;
      afrag[mt][2] = pack8(tA);
      afrag[mt][3] = pack8(tB);
#pragma unroll
      for (int ks = 6; ks < 8; ++ks) {
        const float* src = g + (ks & 1) * 32 + q * 8;
        float tmp[8];
        *(f32x4*)(tmp) = *(const f32x4*)(src);
        *(f32x4*)(tmp + 4) = *(const f32x4*)(src + 4);
        afrag[mt][ks] = pack8(tmp);
      }
    }
#pragma unroll
    for (int ks = 0; ks < 8; ++ks) {
#pragma unroll
      for (int nt = 0; nt < 8; ++nt) {
        bf16x8 bf = lW1[(ks * 8 + nt) * 64 + l];
        acc1[0][nt] = MFMA(afrag[0][ks], bf, acc1[0][nt]);
        acc1[1][nt] = MFMA(afrag[1][ks], bf, acc1[1][nt]);
      }
    }
#pragma unroll
    for (int nt = 0; nt < 8; ++nt) {
      const int h = nt * 16 + c;
      const float b1 = ba1[h];
#pragma unroll
      for (int mt = 0; mt < 2; ++mt)
#pragma unroll
        for (int r = 0; r < 4; ++r)
          hb[(mt * 16 + q * 4 + r) * 132 + h] =
              (__bf16)softplus_f(acc1[mt][nt][r] + b1);
    }
  }
  __syncthreads();

  float colpart[4] = {0.f, 0.f, 0.f, 0.f};
  if (active) {
    bf16x8 a2[2][4];
#pragma unroll
    for (int mt = 0; mt < 2; ++mt)
#pragma unroll
      for (int k2 = 0; k2 < 4; ++k2) {
        const __bf16* p = hb + (mt * 16 + c) * 132 + k2 * 32 + q * 8;
        union { unsigned long long u[2]; bf16x8 v; } tmp;
        tmp.u[0] = *(const unsigned long long*)(p);
        tmp.u[1] = *(const unsigned long long*)(p + 4);
        a2[mt][k2] = tmp.v;
      }
    f32x4 acc2[2][4] = {};
#pragma unroll
    for (int k2 = 0; k2 < 4; ++k2)
#pragma unroll
      for (int nt2 = 0; nt2 < 4; ++nt2) {
        bf16x8 bf = lW2[(k2 * 4 + nt2) * 64 + l];
        acc2[0][nt2] = MFMA(a2[0][k2], bf, acc2[0][nt2]);
        acc2[1][nt2] = MFMA(a2[1][k2], bf, acc2[1][nt2]);
      }
#pragma unroll
    for (int nt2 = 0; nt2 < 4; ++nt2) {
      const int col = nt2 * 16 + c;
      const float b2 = ba2[col];
#pragma unroll
      for (int mt = 0; mt < 2; ++mt)
#pragma unroll
        for (int r = 0; r < 4; ++r) {
          const int a = base + mt * 16 + q * 4 + r;
          float v = acc2[mt][nt2][r] + b2 + atom_f[(size_t)a * FDIM + col];
          out_atoms[(size_t)a * FDIM + col] = v;
          colpart[nt2] += v;
        }
    }
  }
#pragma unroll
  for (int nt2 = 0; nt2 < 4; ++nt2) {
    colpart[nt2] += __shfl_xor(colpart[nt2], 16, 64);
    colpart[nt2] += __shfl_xor(colpart[nt2], 32, 64);
  }
  if (l < 16)
#pragma unroll
    for (int nt2 = 0; nt2 < 4; ++nt2) csum[w][nt2 * 16 + l] = colpart[nt2];
  __syncthreads();
  if (t < 64) {
    float s = 0.f;
#pragma unroll
    for (int wv = 0; wv < 8; ++wv) s += csum[wv][t];
    psums[(size_t)blockIdx.x * 64 + t] = s;
  }
}

// ---------------------------------------------------------------------------
// Parallel tree reduce: src is [nrows][64], dst row per block.
// Thread (seg=t>>6, col=t&63) sums rows r = blk*4+seg, step gridDim*4.
// ---------------------------------------------------------------------------
__global__ void reduce_kernel(const float* __restrict__ src, int nrows,
                              float* __restrict__ dst) {
  __shared__ float part[4][64];
  const int t = threadIdx.x;
  const int seg = t >> 6, col = t & 63;
  const int step = gridDim.x * 4;
  float s = 0.f;
  for (int r = blockIdx.x * 4 + seg; r < nrows; r += step)
    s += src[(size_t)r * 64 + col];
  part[seg][col] = s;
  __syncthreads();
  if (t < 64)
    dst[(size_t)blockIdx.x * 64 + t] =
        part[0][t] + part[1][t] + part[2][t] + part[3][t];
}

// ---------------------------------------------------------------------------
// Global update: sum small reduced arrays -> pooled means -> tiny fp32 MLP
// ---------------------------------------------------------------------------
__global__ void global_kernel(const float* __restrict__ g,
                              const float* __restrict__ Wg1,
                              const float* __restrict__ bg1,
                              const float* __restrict__ Wg2,
                              const float* __restrict__ bg2,
                              const float* __restrict__ bond_r,  // 32 rows
                              const float* __restrict__ atom_r,  // 8 rows
                              float* __restrict__ out_global) {
  __shared__ float combg[192];
  __shared__ float hid[128];
  const int t = threadIdx.x;

  if (t < 64) {
    float s = 0.f;
#pragma unroll
    for (int r = 0; r < 32; ++r) s += bond_r[r * 64 + t];
    combg[64 + t] = s / (float)NB;
    float sa = 0.f;
#pragma unroll
    for (int r = 0; r < 8; ++r) sa += atom_r[r * 64 + t];
    combg[t] = sa / (float)NA;
    combg[128 + t] = g[t];
  }
  __syncthreads();

  if (t < 128) {
    float s = bg1[t];
    for (int k = 0; k < 192; ++k) s += combg[k] * Wg1[k * 128 + t];
    hid[t] = softplus_f(s);
  }
  __syncthreads();
  if (t < 64) {
    float s = bg2[t];
    for (int h = 0; h < 128; ++h) s += hid[h] * Wg2[h * 64 + t];
    out_global[t] = s + g[t];
  }
}

// ---------------------------------------------------------------------------
extern "C" void kernel_launch(void* const* d_in, const int* in_sizes, int n_in,
                              void* d_out, int out_size, void* d_ws, size_t ws_size,
                              hipStream_t stream) {
  (void)in_sizes; (void)n_in; (void)out_size; (void)ws_size;
  const float* atom_f = (const float*)d_in[0];
  const float* bond_f = (const float*)d_in[1];
  const float* g      = (const float*)d_in[2];
  const float* Wb1 = (const float*)d_in[3];
  const float* bb1 = (const float*)d_in[4];
  const float* Wb2 = (const float*)d_in[5];
  const float* bb2 = (const float*)d_in[6];
  const float* Wa1 = (const float*)d_in[7];
  const float* ba1 = (const float*)d_in[8];
  const float* Wa2 = (const float*)d_in[9];
  const float* ba2 = (const float*)d_in[10];
  const float* Wg1 = (const float*)d_in[11];
  const float* bg1 = (const float*)d_in[12];
  const float* Wg2 = (const float*)d_in[13];
  const float* bg2 = (const float*)d_in[14];
  const int* ab_idx = (const int*)d_in[15];
  const int* ba_idx = (const int*)d_in[16];

  float* out        = (float*)d_out;
  float* out_atoms  = out;
  float* out_bonds  = out + (size_t)NA * FDIM;
  float* out_global = out + (size_t)NA * FDIM + (size_t)NB * FDIM;

  const int nb_blocks = NB / 256;                // 3125
  const int na_blocks = (NA + 255) / 256;        // 391

  bf16x8* wp     = (bf16x8*)d_ws;
  float* ws_f    = (float*)d_ws;
  float* bond_ps = ws_f + 40960;                 // 3125 * 64
  float* atom_ps = bond_ps + (size_t)nb_blocks * 64;  // 391 * 64
  float* bond_r  = atom_ps + (size_t)na_blocks * 64;  // 32 * 64
  float* atom_r  = bond_r + 32 * 64;                  // 8 * 64

  pack_kernel<<<40, 256, 0, stream>>>(Wb1, Wb2, Wa1, Wa2, wp);
  bond_kernel<<<nb_blocks, 512, 0, stream>>>(atom_f, bond_f, g, bb1, bb2, ab_idx,
                                             wp, wp + 4096, out_bonds, bond_ps);
  atom_kernel<<<na_blocks, 512, 0, stream>>>(atom_f, g, ba1, ba2, ba_idx,
                                             out_bonds, wp + 5120, wp + 9216,
                                             out_atoms, atom_ps);
  reduce_kernel<<<32, 256, 0, stream>>>(bond_ps, nb_blocks, bond_r);
  reduce_kernel<<<8, 256, 0, stream>>>(atom_ps, na_blocks, atom_r);
  global_kernel<<<1, 256, 0, stream>>>(g, Wg1, bg1, Wg2, bg2, bond_r, atom_r,
                                       out_global);
}